// Round 1
// baseline (82.543 us; speedup 1.0000x reference)
//
#include <hip/hip_runtime.h>
#include <hip/hip_bf16.h>

// out = x @ W^T + bias (memristor constants cancel exactly).
// M=512, N=2048, K=2048 fp32 -> bf16 MFMA, fp32 accum.
//
// Round-3 design (two kernels):
//  K1 convert_bf16: one-shot fp32->bf16 of x and W into d_ws (removes the
//     13x-redundant in-GEMM conversion + halves GEMM global bytes).
//  K2 memristor_gemm: 64x64 tile/CU (grid 32x8=256), 8 waves = 2x2 spatial
//     x 2-way K-split. BK=128, LDS TRIPLE-buffered, staged with
//     global_load_lds(16B) and counted s_waitcnt vmcnt(4) + raw s_barrier
//     (loads for tile t+2 stay in flight across two barriers; never drain
//     to 0 in the main loop). LDS is unpadded (global_load_lds requires a
//     linear dest), so bank conflicts are fixed rule-#21 style: the global
//     SOURCE address carries the inverse XOR swizzle (chunk ^= row&7) and
//     the ds_read applies the same XOR -> 2-way (free).

typedef float  float4_t __attribute__((ext_vector_type(4)));
typedef short  short8_t __attribute__((ext_vector_type(8)));
typedef float  floatx4  __attribute__((ext_vector_type(4)));

constexpr int M = 512, N = 2048, K = 2048;
constexpr int BM = 64, BN = 64, BK = 128;
constexpr int NT = K / BK;              // 16 k-tiles
constexpr int XCHUNKS = M * K / 8;      // 131072 8-elem chunks of x
constexpr int WCHUNKS = N * K / 8;      // 524288 8-elem chunks of W
constexpr int BUFB = BM * BK * 2;       // 16384 B per matrix per LDS buffer

__device__ __forceinline__ void gload16(const void* g, void* l) {
    __builtin_amdgcn_global_load_lds(
        (const __attribute__((address_space(1))) void*)g,
        (__attribute__((address_space(3))) void*)l, 16, 0, 0);
}

// ---------------- kernel 1: fp32 -> bf16 one-shot convert ----------------
__global__ __launch_bounds__(256)
void convert_bf16(const float* __restrict__ x, const float* __restrict__ w,
                  __hip_bfloat16* __restrict__ xb, __hip_bfloat16* __restrict__ wb)
{
    const int i = blockIdx.x * 256 + threadIdx.x;       // one 8-elem chunk
    const float* src;
    __hip_bfloat16* dst;
    size_t off;
    if (i < XCHUNKS) { src = x; dst = xb; off = (size_t)i * 8; }
    else             { src = w; dst = wb; off = (size_t)(i - XCHUNKS) * 8; }
    const float4_t a = *(const float4_t*)(src + off);
    const float4_t b = *(const float4_t*)(src + off + 4);
    union { __hip_bfloat16 h[8]; short8_t s; } u;
    u.h[0] = __float2bfloat16(a.x); u.h[1] = __float2bfloat16(a.y);
    u.h[2] = __float2bfloat16(a.z); u.h[3] = __float2bfloat16(a.w);
    u.h[4] = __float2bfloat16(b.x); u.h[5] = __float2bfloat16(b.y);
    u.h[6] = __float2bfloat16(b.z); u.h[7] = __float2bfloat16(b.w);
    *(short8_t*)(dst + off) = u.s;
}

// ---------------- kernel 2: bf16 GEMM ----------------
__global__ __launch_bounds__(512)
void memristor_gemm(const __hip_bfloat16* __restrict__ xb,
                    const __hip_bfloat16* __restrict__ wb,
                    const float* __restrict__ bias, float* __restrict__ out)
{
    __shared__ __hip_bfloat16 As[3][BM][BK];   // 3 x 16 KiB (unpadded: gload_lds dest)
    __shared__ __hip_bfloat16 Bs[3][BN][BK];   // total 96 KiB

    const int tid  = threadIdx.x;
    const int bn   = blockIdx.x, bm = blockIdx.y;
    const int lane = tid & 63;
    const int wave = tid >> 6;        // 0..7
    const int wsp  = wave & 3;        // spatial quadrant (2x2 of 32x32)
    const int kp   = wave >> 2;       // k-half: kk in [kp*64, kp*64+64)
    const int wm   = (wsp >> 1) * 32;
    const int wn   = (wsp & 1) * 32;
    const int l16  = lane & 15;
    const int quad = lane >> 4;

    // --- staging map: LDS linear chunk L = p*512 + wave*64 + lane, 16B each.
    // LDS (row, cl) holds global chunk (cl ^ (row&7)) of that row (swizzle
    // applied on the SOURCE address; LDS write itself is linear).
    const int srow0 = wave * 4 + (lane >> 4);           // p=0 row (0..31); p=1 adds 32
    const int cl    = lane & 15;
    const int gc    = (cl ^ (srow0 & 7)) * 8;           // (row&7) identical for p=0/1

    const __hip_bfloat16* ga0 = xb + (size_t)(bm * BM + srow0) * K + gc;
    const __hip_bfloat16* ga1 = ga0 + (size_t)32 * K;
    const __hip_bfloat16* gb0 = wb + (size_t)(bn * BN + srow0) * K + gc;
    const __hip_bfloat16* gb1 = gb0 + (size_t)32 * K;

    auto stage = [&](int t, int buf) {                  // 4 global_load_lds / thread
        const size_t go = (size_t)t * BK;
        char* la = (char*)As + buf * BUFB + wave * 1024;  // wave-uniform base (+lane*16 in HW)
        char* lb = (char*)Bs + buf * BUFB + wave * 1024;
        gload16(ga0 + go, la);
        gload16(ga1 + go, la + 8192);
        gload16(gb0 + go, lb);
        gload16(gb1 + go, lb + 8192);
    };

    floatx4 acc[2][2];
    #pragma unroll
    for (int i = 0; i < 2; ++i)
        #pragma unroll
        for (int j = 0; j < 2; ++j)
            acc[i][j] = (floatx4){0.f, 0.f, 0.f, 0.f};

    const int sw  = (l16 & 7) * 16;                     // read-side XOR (all 4 rows share l16&7)
    const int ra0 = (wm + l16) * 256,      ra1 = ra0 + 16 * 256;
    const int rb0 = (wn + l16) * 256,      rb1 = rb0 + 16 * 256;

    auto compute = [&](int buf) {
        const char* ab = (const char*)As + buf * BUFB;
        const char* bb = (const char*)Bs + buf * BUFB;
        #pragma unroll
        for (int s = 0; s < 2; ++s) {
            const int co = ((kp * 8 + s * 4 + quad) * 16) ^ sw;  // swizzled chunk byte
            const short8_t af0 = *(const short8_t*)(ab + ra0 + co);
            const short8_t af1 = *(const short8_t*)(ab + ra1 + co);
            const short8_t bf0 = *(const short8_t*)(bb + rb0 + co);
            const short8_t bf1 = *(const short8_t*)(bb + rb1 + co);
            acc[0][0] = __builtin_amdgcn_mfma_f32_16x16x32_bf16(af0, bf0, acc[0][0], 0, 0, 0);
            acc[0][1] = __builtin_amdgcn_mfma_f32_16x16x32_bf16(af0, bf1, acc[0][1], 0, 0, 0);
            acc[1][0] = __builtin_amdgcn_mfma_f32_16x16x32_bf16(af1, bf0, acc[1][0], 0, 0, 0);
            acc[1][1] = __builtin_amdgcn_mfma_f32_16x16x32_bf16(af1, bf1, acc[1][1], 0, 0, 0);
        }
    };

    // --- prologue: 2 tiles in flight, drain only tile 0's 4 loads ---
    stage(0, 0);
    stage(1, 1);
    asm volatile("s_waitcnt vmcnt(4)" ::: "memory");
    __builtin_amdgcn_s_barrier();
    asm volatile("" ::: "memory");

    // --- main loop: stage t+2, compute t, drain t+1's loads (vmcnt(4)) ---
    int cb = 0, sb = 2;
    for (int t = 0; t < NT - 2; ++t) {
        stage(t + 2, sb);
        compute(cb);
        asm volatile("s_waitcnt vmcnt(4)" ::: "memory");
        __builtin_amdgcn_s_barrier();
        asm volatile("" ::: "memory");
        cb = (cb == 2) ? 0 : cb + 1;
        sb = (sb == 2) ? 0 : sb + 1;
    }
    compute(cb);                                        // t = NT-2
    asm volatile("s_waitcnt vmcnt(0)" ::: "memory");
    __builtin_amdgcn_s_barrier();
    asm volatile("" ::: "memory");
    cb = (cb == 2) ? 0 : cb + 1;
    compute(cb);                                        // t = NT-1
    __syncthreads();                                    // full drain before LDS reuse

    // --- epilogue: 2-way K-split reduction through LDS (reuse As memory) ---
    float* scrb = (float*)As;                           // 18432 B < 48 KiB
    if (kp == 1) {
        #pragma unroll
        for (int i = 0; i < 2; ++i)
            #pragma unroll
            for (int j = 0; j < 2; ++j) {
                float* p = scrb + ((wsp * 32 + j * 16 + l16) * 36 + i * 16 + quad * 4);
                *(floatx4*)p = acc[i][j];
            }
    }
    __syncthreads();
    if (kp == 0) {
        #pragma unroll
        for (int j = 0; j < 2; ++j) {
            const int col = bn * BN + wn + j * 16 + l16;
            const float bv = bias[col];
            #pragma unroll
            for (int i = 0; i < 2; ++i) {
                const floatx4 part = *(const floatx4*)(
                    scrb + ((wsp * 32 + j * 16 + l16) * 36 + i * 16 + quad * 4));
                const int row0 = bm * BM + wm + i * 16 + quad * 4;
                #pragma unroll
                for (int r = 0; r < 4; ++r)
                    out[(size_t)(row0 + r) * N + col] = acc[i][j][r] + part[r] + bv;
            }
        }
    }
}

extern "C" void kernel_launch(void* const* d_in, const int* in_sizes, int n_in,
                              void* d_out, int out_size, void* d_ws, size_t ws_size,
                              hipStream_t stream) {
    const float* x    = (const float*)d_in[0];   // (512, 2048)
    const float* w    = (const float*)d_in[1];   // (2048, 2048) = (N, K)
    const float* bias = (const float*)d_in[2];   // (2048,)
    float* out = (float*)d_out;                  // (512, 2048)

    // workspace: bf16 x (2 MiB) then bf16 W (8 MiB); ws is 256 MiB (poison fill)
    __hip_bfloat16* xbf = (__hip_bfloat16*)d_ws;
    __hip_bfloat16* wbf = xbf + (size_t)M * K;

    convert_bf16<<<(XCHUNKS + WCHUNKS) / 256, 256, 0, stream>>>(x, w, xbf, wbf);

    dim3 grid(N / BN, M / BM);                   // (32, 8) = 256 blocks, 1 per CU
    memristor_gemm<<<grid, 512, 0, stream>>>(xbf, wbf, bias, out);
}